// Round 1
// baseline (39.815 us; speedup 1.0000x reference)
//
#include <hip/hip_runtime.h>

// MemoryLayer: B=4, S=2048, IN_DIM=1024, OUT_DIM=2048, K=64, CHUNK=16,
// OUT_CHUNK=32, TAU=16, N_BUCKETS=65536, T=1.0
constexpr int IN_DIM    = 1024;
constexpr int OUT_DIM   = 2048;
constexpr int K         = 64;
constexpr int CHUNK     = 16;
constexpr int OUT_CHUNK = 32;
constexpr int ROWS      = 4 * 2048;   // B*S
constexpr int NBUCKETS  = 65536;

__global__ __launch_bounds__(256) void
memlayer_kernel(const float* __restrict__ x,
                const float* __restrict__ tables,
                float* __restrict__ out)
{
    const int g   = blockIdx.x * 256 + threadIdx.x;  // one thread per (row, k)
    const int row = g >> 6;
    const int k   = g & 63;

    const float* xr = x + (size_t)row * IN_DIM + k * CHUNK;

    // Load 16 contiguous floats (64 B) as 4x float4.
    float4 x0 = reinterpret_cast<const float4*>(xr)[0];
    float4 x1 = reinterpret_cast<const float4*>(xr)[1];
    float4 x2 = reinterpret_cast<const float4*>(xr)[2];
    float4 x3 = reinterpret_cast<const float4*>(xr)[3];

    // h: bit for element idx gets weight 2^(15-idx); p = prod sigmoid(2*x_i)
    unsigned h = 0;
    float denom = 1.0f;
#define PROC(v, idx)                                              \
    do {                                                          \
        h |= ((v) >= 0.0f ? 1u : 0u) << (15 - (idx));             \
        denom *= 1.0f + __expf(-2.0f * (v));                      \
    } while (0)
    PROC(x0.x,  0); PROC(x0.y,  1); PROC(x0.z,  2); PROC(x0.w,  3);
    PROC(x1.x,  4); PROC(x1.y,  5); PROC(x1.z,  6); PROC(x1.w,  7);
    PROC(x2.x,  8); PROC(x2.y,  9); PROC(x2.z, 10); PROC(x2.w, 11);
    PROC(x3.x, 12); PROC(x3.y, 13); PROC(x3.z, 14); PROC(x3.w, 15);
#undef PROC
    const float p = 1.0f / denom;   // inf -> 0, correct underflow limit

    const float4* trow = reinterpret_cast<const float4*>(
        tables + ((size_t)k * NBUCKETS + (size_t)h) * OUT_CHUNK);
    float4* orow = reinterpret_cast<float4*>(
        out + (size_t)row * OUT_DIM + k * OUT_CHUNK);

#pragma unroll
    for (int j = 0; j < 8; ++j) {
        float4 t = trow[j];
        float4 o;
        o.x = t.x * p;
        o.y = t.y * p;
        o.z = t.z * p;
        o.w = t.w * p;
        orow[j] = o;
    }
}

extern "C" void kernel_launch(void* const* d_in, const int* in_sizes, int n_in,
                              void* d_out, int out_size, void* d_ws, size_t ws_size,
                              hipStream_t stream)
{
    const float* x      = (const float*)d_in[0];
    const float* tables = (const float*)d_in[1];
    float*       out    = (float*)d_out;

    const int total  = ROWS * K;          // 524288 threads
    const int block  = 256;
    const int grid   = total / block;     // 2048 blocks

    memlayer_kernel<<<grid, block, 0, stream>>>(x, tables, out);
}

// Round 3
// 30.614 us; speedup vs baseline: 1.3006x; 1.3006x over previous
//
#include <hip/hip_runtime.h>

// MemoryLayer: B=4, S=2048, IN_DIM=1024, OUT_DIM=2048, K=64, CHUNK=16,
// OUT_CHUNK=32, TAU=16, N_BUCKETS=65536, T=1.0
constexpr int IN_DIM    = 1024;
constexpr int OUT_DIM   = 2048;
constexpr int K         = 64;
constexpr int CHUNK     = 16;
constexpr int OUT_CHUNK = 32;
constexpr int ROWS      = 4 * 2048;   // B*S
constexpr int NBUCKETS  = 65536;

__global__ __launch_bounds__(256) void
memlayer_kernel(const float* __restrict__ x,
                const float* __restrict__ tables,
                float* __restrict__ out)
{
    const int g    = blockIdx.x * 256 + threadIdx.x;
    const int row  = g >> 6;           // one wave per x-row
    const int lane = threadIdx.x & 63; // = k in phase 1

    const float* xr = x + (size_t)row * IN_DIM + lane * CHUNK;

    // Phase 1: each lane computes hash h and gate p for its own k = lane.
    float4 x0 = reinterpret_cast<const float4*>(xr)[0];
    float4 x1 = reinterpret_cast<const float4*>(xr)[1];
    float4 x2 = reinterpret_cast<const float4*>(xr)[2];
    float4 x3 = reinterpret_cast<const float4*>(xr)[3];

    unsigned h = 0;
    float denom = 1.0f;
#define PROC(v, idx)                                              \
    do {                                                          \
        h |= ((v) >= 0.0f ? 1u : 0u) << (15 - (idx));             \
        denom *= 1.0f + __expf(-2.0f * (v));                      \
    } while (0)
    PROC(x0.x,  0); PROC(x0.y,  1); PROC(x0.z,  2); PROC(x0.w,  3);
    PROC(x1.x,  4); PROC(x1.y,  5); PROC(x1.z,  6); PROC(x1.w,  7);
    PROC(x2.x,  8); PROC(x2.y,  9); PROC(x2.z, 10); PROC(x2.w, 11);
    PROC(x3.x, 12); PROC(x3.y, 13); PROC(x3.z, 14); PROC(x3.w, 15);
#undef PROC
    const float p = 1.0f / denom;   // inf -> 0, correct underflow limit

    // Phase 2: 8 lanes cooperate per table row. sub = 16B segment index.
    const int kg  = lane >> 3;      // which k within this pass
    const int sub = lane & 7;       // float4 index within the 32-float row

    float4* orow = reinterpret_cast<float4*>(out + (size_t)row * OUT_DIM);

#pragma unroll
    for (int pass = 0; pass < 8; ++pass) {
        const int src = pass * 8 + kg;                 // lane holding (h,p) for k=src
        const unsigned hk = (unsigned)__shfl((int)h, src, 64);
        const float    pk = __shfl(p, src, 64);

        const float4* trow = reinterpret_cast<const float4*>(
            tables + ((size_t)src * NBUCKETS + (size_t)hk) * OUT_CHUNK);
        float4 t = trow[sub];                          // 8 lanes -> one 128B line

        float4 o;
        o.x = t.x * pk; o.y = t.y * pk; o.z = t.z * pk; o.w = t.w * pk;
        // float4 index = src*8 + sub = (pass*8+kg)*8 + (lane&7) = pass*64 + lane
        orow[pass * 64 + lane] = o;
    }
}

extern "C" void kernel_launch(void* const* d_in, const int* in_sizes, int n_in,
                              void* d_out, int out_size, void* d_ws, size_t ws_size,
                              hipStream_t stream)
{
    const float* x      = (const float*)d_in[0];
    const float* tables = (const float*)d_in[1];
    float*       out    = (float*)d_out;

    const int total  = ROWS * K;          // 524288 threads
    const int block  = 256;
    const int grid   = total / block;     // 2048 blocks

    memlayer_kernel<<<grid, block, 0, stream>>>(x, tables, out);
}